// Round 3
// baseline (2238.786 us; speedup 1.0000x reference)
//
#include <hip/hip_runtime.h>
#include <hip/hip_bf16.h>
#include <math.h>

#define BB 2
#define SS 2048
#define EE 2048
#define NQ 16
#define NKV 4
#define HD 128
#define WINDOW 512

typedef __hip_bfloat16 bf16;

__device__ __forceinline__ float toF(float v) { return v; }
__device__ __forceinline__ float toF(bf16 v) { return __bfloat162float(v); }
__device__ __forceinline__ void storeOut(float* p, float v) { *p = v; }
__device__ __forceinline__ void storeOut(bf16* p, float v) { *p = __float2bfloat16(v); }

// ---------------------------------------------------------------------------
// Tiled GEMM: Y[M,N] = A[M,K] @ W[K,N] + bias[N]   (fp32 accumulate)
// BM=64, BN=64, BK=16, 256 threads, 4x4 per thread.
// ---------------------------------------------------------------------------
template <typename TA, typename TW, typename TO>
__global__ __launch_bounds__(256) void gemm_bias(const TA* __restrict__ A,
                                                 const TW* __restrict__ W,
                                                 const float* __restrict__ bias,
                                                 TO* __restrict__ Y,
                                                 int M, int N, int K) {
    __shared__ float As[64][17];
    __shared__ float Ws[16][68];
    const int t  = threadIdx.x;
    const int tx = t & 15;
    const int ty = t >> 4;
    const int row0 = blockIdx.y * 64;
    const int col0 = blockIdx.x * 64;

    float acc[4][4];
#pragma unroll
    for (int i = 0; i < 4; i++)
#pragma unroll
        for (int j = 0; j < 4; j++) acc[i][j] = 0.f;

    const int ar = t >> 2;            // 0..63
    const int ac = (t & 3) * 4;       // 0,4,8,12
    const int wr = t >> 4;            // 0..15
    const int wc = (t & 15) * 4;      // 0..60

    for (int k0 = 0; k0 < K; k0 += 16) {
        const TA* ap = A + (size_t)(row0 + ar) * K + k0 + ac;
#pragma unroll
        for (int j = 0; j < 4; j++) As[ar][ac + j] = toF(ap[j]);
        const TW* wp = W + (size_t)(k0 + wr) * N + col0 + wc;
#pragma unroll
        for (int j = 0; j < 4; j++) Ws[wr][wc + j] = toF(wp[j]);
        __syncthreads();
#pragma unroll
        for (int kk = 0; kk < 16; kk++) {
            float a[4], b[4];
#pragma unroll
            for (int i = 0; i < 4; i++) a[i] = As[ty * 4 + i][kk];
#pragma unroll
            for (int j = 0; j < 4; j++) b[j] = Ws[kk][tx * 4 + j];
#pragma unroll
            for (int i = 0; i < 4; i++)
#pragma unroll
                for (int j = 0; j < 4; j++) acc[i][j] = fmaf(a[i], b[j], acc[i][j]);
        }
        __syncthreads();
    }

#pragma unroll
    for (int i = 0; i < 4; i++) {
        int r = row0 + ty * 4 + i;
#pragma unroll
        for (int j = 0; j < 4; j++) {
            int c = col0 + tx * 4 + j;
            storeOut(Y + (size_t)r * N + c, acc[i][j] + bias[c]);
        }
    }
}

// ---------------------------------------------------------------------------
// RoPE in-place on bf16 buffer laid out (B*S rows, H heads, HD).
// ---------------------------------------------------------------------------
__global__ void rope_kernel(bf16* __restrict__ buf, int H) {
    int idx = blockIdx.x * blockDim.x + threadIdx.x;
    int total = BB * SS * H * (HD / 2);
    if (idx >= total) return;
    int d2 = idx & 63;               // HD/2 = 64
    int hh = idx >> 6;
    int h = hh % H;
    int row = hh / H;
    int s = row % SS;
    float freq = expf(-logf(10000.f) * (float)(2 * d2) / (float)HD);
    float ang = (float)s * freq;
    float c = cosf(ang), sn = sinf(ang);
    size_t base = ((size_t)row * H + h) * HD + 2 * d2;
    float xe = toF(buf[base]);
    float xo = toF(buf[base + 1]);
    buf[base]     = __float2bfloat16(xe * c - xo * sn);
    buf[base + 1] = __float2bfloat16(xe * sn + xo * c);
}

// ---------------------------------------------------------------------------
// Windowed causal flash attention with GQA. IN-PLACE: Oout aliases Q —
// each block stages its private Q tile (b, q0..q0+31, h, :) into LDS first
// and only writes those same elements at the very end.
// ---------------------------------------------------------------------------
__global__ __launch_bounds__(256) void attn_kernel(const bf16* __restrict__ Q,
                                                   const bf16* __restrict__ K,
                                                   const bf16* __restrict__ V,
                                                   bf16* __restrict__ Oout) {
    __shared__ float qs[32][129];
    __shared__ float ks[32][129];
    __shared__ float vs[32][129];
    __shared__ float sc[32][33];
    __shared__ float mrow[32], lrow[32], arow[32];

    const int t = threadIdx.x;
    const int q0 = blockIdx.x * 32;
    const int h = blockIdx.y;
    const int b = blockIdx.z;
    const int hkv = h >> 2;                    // NQ/NKV = 4
    const float scale = 0.08838834764831845f;  // 1/sqrt(128)

    for (int i = t; i < 32 * 128; i += 256) {
        int qi = i >> 7, d = i & 127;
        qs[qi][d] = toF(Q[(((size_t)b * SS + q0 + qi) * NQ + h) * HD + d]) * scale;
    }
    if (t < 32) { mrow[t] = -__builtin_huge_valf(); lrow[t] = 0.f; }

    float O[16];
#pragma unroll
    for (int i = 0; i < 16; i++) O[i] = 0.f;

    const int qi = t >> 3;     // 0..31
    const int u = t & 7;       // 0..7
    const int k0l = u * 4;     // this thread's 4 keys in score phase

    int jstart = q0 - WINDOW;
    if (jstart < 0) jstart = 0;
    __syncthreads();

    for (int c0 = jstart; c0 <= q0; c0 += 32) {
        // stage K/V chunk
        for (int i = t; i < 32 * 128; i += 256) {
            int kj = i >> 7, d = i & 127;
            size_t gbase = (((size_t)b * SS + c0 + kj) * NKV + hkv) * HD + d;
            ks[kj][d] = toF(K[gbase]);
            vs[kj][d] = toF(V[gbase]);
        }
        __syncthreads();

        // scores: each thread computes 4 keys for its query row
        float s0 = 0.f, s1 = 0.f, s2 = 0.f, s3 = 0.f;
#pragma unroll 8
        for (int d = 0; d < 128; d++) {
            float qv = qs[qi][d];
            s0 = fmaf(qv, ks[k0l + 0][d], s0);
            s1 = fmaf(qv, ks[k0l + 1][d], s1);
            s2 = fmaf(qv, ks[k0l + 2][d], s2);
            s3 = fmaf(qv, ks[k0l + 3][d], s3);
        }
        const int iq = q0 + qi;
        float sv[4] = {s0, s1, s2, s3};
#pragma unroll
        for (int j = 0; j < 4; j++) {
            int jk = c0 + k0l + j;
            sc[qi][k0l + j] = (jk > iq || iq - jk > WINDOW) ? -__builtin_huge_valf() : sv[j];
        }
        __syncthreads();

        // online softmax per query row
        if (t < 32) {
            float mo = mrow[t], mx = mo;
#pragma unroll
            for (int j = 0; j < 32; j++) mx = fmaxf(mx, sc[t][j]);
            mx = fmaxf(mx, -1e30f);   // never -inf even if a chunk were all-masked
            float alpha = expf(mo - mx);
            float sum = 0.f;
#pragma unroll
            for (int j = 0; j < 32; j++) {
                float p = expf(sc[t][j] - mx);
                sc[t][j] = p;
                sum += p;
            }
            mrow[t] = mx;
            lrow[t] = lrow[t] * alpha + sum;
            arow[t] = alpha;
        }
        __syncthreads();

        // O update
        float alpha = arow[qi];
#pragma unroll
        for (int dd = 0; dd < 16; dd++) O[dd] *= alpha;
        for (int kj = 0; kj < 32; kj++) {
            float p = sc[qi][kj];
#pragma unroll
            for (int dd = 0; dd < 16; dd++) O[dd] = fmaf(p, vs[kj][u + 8 * dd], O[dd]);
        }
        __syncthreads();
    }

    float linv = 1.f / lrow[qi];
#pragma unroll
    for (int dd = 0; dd < 16; dd++) {
        Oout[(((size_t)b * SS + q0 + qi) * NQ + h) * HD + u + 8 * dd] =
            __float2bfloat16(O[dd] * linv);
    }
}

// ---------------------------------------------------------------------------
extern "C" void kernel_launch(void* const* d_in, const int* in_sizes, int n_in,
                              void* d_out, int out_size, void* d_ws, size_t ws_size,
                              hipStream_t stream) {
    // Reference dtypes are ALL float32 (setup_inputs uses jnp.float32).
    const float* x  = (const float*)d_in[0];
    const float* Wq = (const float*)d_in[1];
    const float* bq = (const float*)d_in[2];
    const float* Wk = (const float*)d_in[3];
    const float* bk = (const float*)d_in[4];
    const float* Wv = (const float*)d_in[5];
    const float* bv = (const float*)d_in[6];
    const float* Wo = (const float*)d_in[7];
    const float* bo = (const float*)d_in[8];
    float* out = (float*)d_out;

    const int M = BB * SS;           // 4096
    const int DQ = NQ * HD;          // 2048
    const int DKV = NKV * HD;        // 512

    // workspace (bf16): Q/attn-out 16.78 MB + K 4.19 MB + V 4.19 MB = 25.2 MB
    bf16* Qb = (bf16*)d_ws;
    bf16* Kb = Qb + (size_t)M * DQ;
    bf16* Vb = Kb + (size_t)M * DKV;

    // 1. QKV projections (fp32 in, bf16 out)
    gemm_bias<float, float, bf16><<<dim3(DQ / 64, M / 64), 256, 0, stream>>>(
        x, Wq, bq, Qb, M, DQ, EE);
    gemm_bias<float, float, bf16><<<dim3(DKV / 64, M / 64), 256, 0, stream>>>(
        x, Wk, bk, Kb, M, DKV, EE);
    gemm_bias<float, float, bf16><<<dim3(DKV / 64, M / 64), 256, 0, stream>>>(
        x, Wv, bv, Vb, M, DKV, EE);

    // 2. RoPE on Q and K
    {
        int totQ = BB * SS * NQ * (HD / 2);
        rope_kernel<<<(totQ + 255) / 256, 256, 0, stream>>>(Qb, NQ);
        int totK = BB * SS * NKV * (HD / 2);
        rope_kernel<<<(totK + 255) / 256, 256, 0, stream>>>(Kb, NKV);
    }

    // 3. Windowed flash attention (in-place: output overwrites Qb)
    attn_kernel<<<dim3(SS / 32, NQ, BB), 256, 0, stream>>>(Qb, Kb, Vb, Qb);

    // 4. Output projection (bf16 A, fp32 W, fp32 out)
    gemm_bias<bf16, float, float><<<dim3(EE / 64, M / 64), 256, 0, stream>>>(
        Qb, Wo, bo, out, M, EE, DQ);
}

// Round 4
// 1067.186 us; speedup vs baseline: 2.0978x; 2.0978x over previous
//
#include <hip/hip_runtime.h>
#include <hip/hip_bf16.h>
#include <math.h>

#define BB 2
#define SS 2048
#define EE 2048
#define NQ 16
#define NKV 4
#define HD 128
#define WINDOW 512

typedef __hip_bfloat16 bf16;
typedef short short8 __attribute__((ext_vector_type(8)));   // 8 bf16 (4 VGPRs)
typedef float f32x4 __attribute__((ext_vector_type(4)));

__device__ __forceinline__ float toF(bf16 v) { return __bfloat162float(v); }
__device__ __forceinline__ bf16 toB(float v) { return __float2bfloat16(v); }

// async global->LDS, 16B per lane. LDS dest = wave-uniform base + lane*16.
__device__ __forceinline__ void gld_lds16(const void* g, void* l) {
    __builtin_amdgcn_global_load_lds(
        (const __attribute__((address_space(1))) void*)g,
        (__attribute__((address_space(3))) void*)l, 16, 0, 0);
}

// ---------------------------------------------------------------------------
// fp32 -> bf16 elementwise (n % 4 == 0)
// ---------------------------------------------------------------------------
__global__ __launch_bounds__(256) void convert_bf16(const float* __restrict__ in,
                                                    bf16* __restrict__ out, int n) {
    int i = (blockIdx.x * 256 + threadIdx.x) * 4;
    if (i >= n) return;
    const float4 v = *(const float4*)(in + i);
    bf16 o[4] = {toB(v.x), toB(v.y), toB(v.z), toB(v.w)};
    *(uint2*)(out + i) = *(const uint2*)o;
}

// ---------------------------------------------------------------------------
// fp32 [K][N] -> bf16 [N][K] (transpose + convert). K,N multiples of 32.
// ---------------------------------------------------------------------------
__global__ __launch_bounds__(256) void convert_transpose(const float* __restrict__ in,
                                                         bf16* __restrict__ out,
                                                         int K, int N) {
    __shared__ float tile[32][33];
    const int t = threadIdx.x;
    const int tx = t & 31, ty = t >> 5;   // 32 x 8
    const int n0 = blockIdx.x * 32, k0 = blockIdx.y * 32;
#pragma unroll
    for (int r = 0; r < 4; r++) {
        int k = k0 + ty + r * 8;
        tile[ty + r * 8][tx] = in[(size_t)k * N + n0 + tx];
    }
    __syncthreads();
#pragma unroll
    for (int r = 0; r < 4; r++) {
        int n = n0 + ty + r * 8;
        out[(size_t)n * K + k0 + tx] = toB(tile[tx][ty + r * 8]);
    }
}

// ---------------------------------------------------------------------------
// MFMA bf16 GEMM, m97 structure: 128x128 tile, BK=32, 256 threads (4 waves,
// 2x2), each wave 4x4 grid of 16x16x32 MFMAs. A [M,K] bf16 row-major,
// BT [N,K] bf16 row-major (B transposed). global_load_lds width-16 staging.
// MODE 0: Yf = fp32 out [M,N] + bias b0.
// MODE 1: QKV split -> bf16 Yq/Yk/Yv with biases b0/b1/b2 (N=3072 packed).
// ---------------------------------------------------------------------------
template <int MODE>
__global__ __launch_bounds__(256) void mfma_gemm(
    const bf16* __restrict__ A, const bf16* __restrict__ BT,
    const float* __restrict__ b0, const float* __restrict__ b1,
    const float* __restrict__ b2,
    float* __restrict__ Yf,
    bf16* __restrict__ Yq, bf16* __restrict__ Yk, bf16* __restrict__ Yv,
    int M, int N, int K) {
    __shared__ bf16 As[128 * 32];   // [row][k] 64B rows, unpadded (gld_lds order)
    __shared__ bf16 Bs[128 * 32];   // [n]  [k] 64B rows

    const int t = threadIdx.x;
    const int lane = t & 63;
    const int w = t >> 6;            // wave 0..3
    const int wm = w >> 1, wn = w & 1;
    const int m0 = blockIdx.y * 128, n0 = blockIdx.x * 128;

    const int srow = lane >> 2;          // 0..15 within 16-row chunk
    const int scol = (lane & 3) * 8;     // element offset in row (x8 bf16 = 16B)

    f32x4 acc[4][4];
#pragma unroll
    for (int i = 0; i < 4; i++)
#pragma unroll
        for (int j = 0; j < 4; j++) acc[i][j] = (f32x4)0.f;

    const int lr = lane & 15;            // fragment row/col
    const int lq = lane >> 4;            // quad 0..3

    for (int k0 = 0; k0 < K; k0 += 32) {
#pragma unroll
        for (int s = 0; s < 2; s++) {
            const int c = w * 2 + s;     // 16-row chunk 0..7
            gld_lds16(A + (size_t)(m0 + c * 16 + srow) * K + k0 + scol, As + c * 512);
            gld_lds16(BT + (size_t)(n0 + c * 16 + srow) * K + k0 + scol, Bs + c * 512);
        }
        __syncthreads();
        short8 af[4], bfv[4];
#pragma unroll
        for (int i = 0; i < 4; i++)
            af[i] = *(const short8*)(As + (wm * 64 + i * 16 + lr) * 32 + lq * 8);
#pragma unroll
        for (int j = 0; j < 4; j++)
            bfv[j] = *(const short8*)(Bs + (wn * 64 + j * 16 + lr) * 32 + lq * 8);
#pragma unroll
        for (int i = 0; i < 4; i++)
#pragma unroll
            for (int j = 0; j < 4; j++)
                acc[i][j] = __builtin_amdgcn_mfma_f32_16x16x32_bf16(af[i], bfv[j],
                                                                    acc[i][j], 0, 0, 0);
        __syncthreads();
    }

    // epilogue: D row = lq*4 + r (M), col = lr (N) within each 16x16 block
    if (MODE == 0) {
#pragma unroll
        for (int j = 0; j < 4; j++) {
            const int col = n0 + wn * 64 + j * 16 + lr;
            const float bj = b0[col];
#pragma unroll
            for (int i = 0; i < 4; i++) {
                const int row = m0 + wm * 64 + i * 16 + lq * 4;
#pragma unroll
                for (int r = 0; r < 4; r++)
                    Yf[(size_t)(row + r) * N + col] = acc[i][j][r] + bj;
            }
        }
    } else {
        bf16* outp; const float* bias; int ldc, c0;
        if (n0 < 2048)      { outp = Yq; bias = b0; ldc = 2048; c0 = n0; }
        else if (n0 < 2560) { outp = Yk; bias = b1; ldc = 512;  c0 = n0 - 2048; }
        else                { outp = Yv; bias = b2; ldc = 512;  c0 = n0 - 2560; }
#pragma unroll
        for (int j = 0; j < 4; j++) {
            const int col = c0 + wn * 64 + j * 16 + lr;
            const float bj = bias[col];
#pragma unroll
            for (int i = 0; i < 4; i++) {
                const int row = m0 + wm * 64 + i * 16 + lq * 4;
#pragma unroll
                for (int r = 0; r < 4; r++)
                    outp[(size_t)(row + r) * ldc + col] = toB(acc[i][j][r] + bj);
            }
        }
    }
}

// ---------------------------------------------------------------------------
// RoPE in-place on bf16 buffer laid out (B*S rows, H heads, HD).
// ---------------------------------------------------------------------------
__global__ void rope_kernel(bf16* __restrict__ buf, int H) {
    int idx = blockIdx.x * blockDim.x + threadIdx.x;
    int total = BB * SS * H * (HD / 2);
    if (idx >= total) return;
    int d2 = idx & 63;               // HD/2 = 64
    int hh = idx >> 6;
    int h = hh % H;
    int row = hh / H;
    int s = row % SS;
    float freq = expf(-logf(10000.f) * (float)(2 * d2) / (float)HD);
    float ang = (float)s * freq;
    float c = cosf(ang), sn = sinf(ang);
    size_t base = ((size_t)row * H + h) * HD + 2 * d2;
    float xe = toF(buf[base]);
    float xo = toF(buf[base + 1]);
    buf[base]     = toB(xe * c - xo * sn);
    buf[base + 1] = toB(xe * sn + xo * c);
}

// ---------------------------------------------------------------------------
// Windowed causal flash attention with GQA (scalar VALU version, unchanged).
// IN-PLACE: Oout aliases Q — each block's Q tile is staged to LDS up front.
// ---------------------------------------------------------------------------
__global__ __launch_bounds__(256) void attn_kernel(const bf16* __restrict__ Q,
                                                   const bf16* __restrict__ K,
                                                   const bf16* __restrict__ V,
                                                   bf16* __restrict__ Oout) {
    __shared__ float qs[32][129];
    __shared__ float ks[32][129];
    __shared__ float vs[32][129];
    __shared__ float sc[32][33];
    __shared__ float mrow[32], lrow[32], arow[32];

    const int t = threadIdx.x;
    const int q0 = blockIdx.x * 32;
    const int h = blockIdx.y;
    const int b = blockIdx.z;
    const int hkv = h >> 2;                    // NQ/NKV = 4
    const float scale = 0.08838834764831845f;  // 1/sqrt(128)

    for (int i = t; i < 32 * 128; i += 256) {
        int qi = i >> 7, d = i & 127;
        qs[qi][d] = toF(Q[(((size_t)b * SS + q0 + qi) * NQ + h) * HD + d]) * scale;
    }
    if (t < 32) { mrow[t] = -__builtin_huge_valf(); lrow[t] = 0.f; }

    float O[16];
#pragma unroll
    for (int i = 0; i < 16; i++) O[i] = 0.f;

    const int qi = t >> 3;
    const int u = t & 7;
    const int k0l = u * 4;

    int jstart = q0 - WINDOW;
    if (jstart < 0) jstart = 0;
    __syncthreads();

    for (int c0 = jstart; c0 <= q0; c0 += 32) {
        for (int i = t; i < 32 * 128; i += 256) {
            int kj = i >> 7, d = i & 127;
            size_t gbase = (((size_t)b * SS + c0 + kj) * NKV + hkv) * HD + d;
            ks[kj][d] = toF(K[gbase]);
            vs[kj][d] = toF(V[gbase]);
        }
        __syncthreads();

        float s0 = 0.f, s1 = 0.f, s2 = 0.f, s3 = 0.f;
#pragma unroll 8
        for (int d = 0; d < 128; d++) {
            float qv = qs[qi][d];
            s0 = fmaf(qv, ks[k0l + 0][d], s0);
            s1 = fmaf(qv, ks[k0l + 1][d], s1);
            s2 = fmaf(qv, ks[k0l + 2][d], s2);
            s3 = fmaf(qv, ks[k0l + 3][d], s3);
        }
        const int iq = q0 + qi;
        float sv[4] = {s0, s1, s2, s3};
#pragma unroll
        for (int j = 0; j < 4; j++) {
            int jk = c0 + k0l + j;
            sc[qi][k0l + j] = (jk > iq || iq - jk > WINDOW) ? -__builtin_huge_valf() : sv[j];
        }
        __syncthreads();

        if (t < 32) {
            float mo = mrow[t], mx = mo;
#pragma unroll
            for (int j = 0; j < 32; j++) mx = fmaxf(mx, sc[t][j]);
            mx = fmaxf(mx, -1e30f);
            float alpha = expf(mo - mx);
            float sum = 0.f;
#pragma unroll
            for (int j = 0; j < 32; j++) {
                float p = expf(sc[t][j] - mx);
                sc[t][j] = p;
                sum += p;
            }
            mrow[t] = mx;
            lrow[t] = lrow[t] * alpha + sum;
            arow[t] = alpha;
        }
        __syncthreads();

        float alpha = arow[qi];
#pragma unroll
        for (int dd = 0; dd < 16; dd++) O[dd] *= alpha;
        for (int kj = 0; kj < 32; kj++) {
            float p = sc[qi][kj];
#pragma unroll
            for (int dd = 0; dd < 16; dd++) O[dd] = fmaf(p, vs[kj][u + 8 * dd], O[dd]);
        }
        __syncthreads();
    }

    float linv = 1.f / lrow[qi];
#pragma unroll
    for (int dd = 0; dd < 16; dd++) {
        Oout[(((size_t)b * SS + q0 + qi) * NQ + h) * HD + u + 8 * dd] =
            toB(O[dd] * linv);
    }
}

// ---------------------------------------------------------------------------
extern "C" void kernel_launch(void* const* d_in, const int* in_sizes, int n_in,
                              void* d_out, int out_size, void* d_ws, size_t ws_size,
                              hipStream_t stream) {
    const float* x  = (const float*)d_in[0];
    const float* Wq = (const float*)d_in[1];
    const float* bq = (const float*)d_in[2];
    const float* Wk = (const float*)d_in[3];
    const float* bk = (const float*)d_in[4];
    const float* Wv = (const float*)d_in[5];
    const float* bv = (const float*)d_in[6];
    const float* Wo = (const float*)d_in[7];
    const float* bo = (const float*)d_in[8];
    float* out = (float*)d_out;

    const int M   = BB * SS;   // 4096
    const int DQ  = NQ * HD;   // 2048
    const int DKV = NKV * HD;  // 512
    const int NPK = DQ + 2 * DKV;  // 3072 packed QKV width

    // workspace layout (bf16), total ~63 MB
    bf16* xb     = (bf16*)d_ws;                       // 4096*2048
    bf16* WqkvT  = xb + (size_t)M * EE;               // 3072*2048  (rows: n)
    bf16* WoT    = WqkvT + (size_t)NPK * EE;          // 2048*2048
    bf16* Qb     = WoT + (size_t)EE * DQ;             // 4096*2048 (attn out in-place)
    bf16* Kb     = Qb + (size_t)M * DQ;               // 4096*512
    bf16* Vb     = Kb + (size_t)M * DKV;              // 4096*512

    // 0. convert x -> bf16; weights -> bf16 transposed [N][K]
    convert_bf16<<<(M * EE / 4 + 255) / 256, 256, 0, stream>>>(x, xb, M * EE);
    convert_transpose<<<dim3(DQ / 32, EE / 32), 256, 0, stream>>>(Wq, WqkvT, EE, DQ);
    convert_transpose<<<dim3(DKV / 32, EE / 32), 256, 0, stream>>>(
        Wk, WqkvT + (size_t)DQ * EE, EE, DKV);
    convert_transpose<<<dim3(DKV / 32, EE / 32), 256, 0, stream>>>(
        Wv, WqkvT + (size_t)(DQ + DKV) * EE, EE, DKV);
    convert_transpose<<<dim3(DQ / 32, DQ / 32), 256, 0, stream>>>(Wo, WoT, DQ, EE);

    // 1. fused QKV projection (MFMA)
    mfma_gemm<1><<<dim3(NPK / 128, M / 128), 256, 0, stream>>>(
        xb, WqkvT, bq, bk, bv, nullptr, Qb, Kb, Vb, M, NPK, EE);

    // 2. RoPE on Q and K
    rope_kernel<<<(BB * SS * NQ * (HD / 2) + 255) / 256, 256, 0, stream>>>(Qb, NQ);
    rope_kernel<<<(BB * SS * NKV * (HD / 2) + 255) / 256, 256, 0, stream>>>(Kb, NKV);

    // 3. windowed flash attention (in-place: output overwrites Qb)
    attn_kernel<<<dim3(SS / 32, NQ, BB), 256, 0, stream>>>(Qb, Kb, Vb, Qb);

    // 4. output projection (MFMA, fp32 out)
    mfma_gemm<0><<<dim3(EE / 128, M / 128), 256, 0, stream>>>(
        Qb, WoT, bo, nullptr, nullptr, out, nullptr, nullptr, nullptr, M, EE, DQ);
}

// Round 5
// 378.248 us; speedup vs baseline: 5.9188x; 2.8214x over previous
//
#include <hip/hip_runtime.h>
#include <hip/hip_bf16.h>
#include <math.h>

#define BB 2
#define SS 2048
#define EE 2048
#define NQ 16
#define NKV 4
#define HD 128
#define WINDOW 512

typedef __hip_bfloat16 bf16;
typedef short short8 __attribute__((ext_vector_type(8)));   // 8 bf16 (4 VGPRs)
typedef float f32x4 __attribute__((ext_vector_type(4)));

__device__ __forceinline__ float toF(bf16 v) { return __bfloat162float(v); }
__device__ __forceinline__ bf16 toB(float v) { return __float2bfloat16(v); }

// async global->LDS, 16B per lane. LDS dest = wave-uniform base + lane*16.
__device__ __forceinline__ void gld_lds16(const void* g, void* l) {
    __builtin_amdgcn_global_load_lds(
        (const __attribute__((address_space(1))) void*)g,
        (__attribute__((address_space(3))) void*)l, 16, 0, 0);
}

// ---------------------------------------------------------------------------
// fp32 -> bf16 elementwise (n % 4 == 0)
// ---------------------------------------------------------------------------
__global__ __launch_bounds__(256) void convert_bf16(const float* __restrict__ in,
                                                    bf16* __restrict__ out, int n) {
    int i = (blockIdx.x * 256 + threadIdx.x) * 4;
    if (i >= n) return;
    const float4 v = *(const float4*)(in + i);
    bf16 o[4] = {toB(v.x), toB(v.y), toB(v.z), toB(v.w)};
    *(uint2*)(out + i) = *(const uint2*)o;
}

// ---------------------------------------------------------------------------
// fp32 [K][N] -> bf16 [N][K] (transpose + convert). K,N multiples of 32.
// ---------------------------------------------------------------------------
__global__ __launch_bounds__(256) void convert_transpose(const float* __restrict__ in,
                                                         bf16* __restrict__ out,
                                                         int K, int N) {
    __shared__ float tile[32][33];
    const int t = threadIdx.x;
    const int tx = t & 31, ty = t >> 5;   // 32 x 8
    const int n0 = blockIdx.x * 32, k0 = blockIdx.y * 32;
#pragma unroll
    for (int r = 0; r < 4; r++) {
        int k = k0 + ty + r * 8;
        tile[ty + r * 8][tx] = in[(size_t)k * N + n0 + tx];
    }
    __syncthreads();
#pragma unroll
    for (int r = 0; r < 4; r++) {
        int n = n0 + ty + r * 8;
        out[(size_t)n * K + k0 + tx] = toB(tile[tx][ty + r * 8]);
    }
}

// ---------------------------------------------------------------------------
// MFMA bf16 GEMM (m97 structure): 128x128 tile, BK=32, 4 waves 2x2, each wave
// 4x4 grid of 16x16x32 MFMAs. A [M,K] bf16, BT [N,K] bf16 (B transposed).
// MODE 0: fp32 out + bias. MODE 1: packed QKV split -> bf16 Yq/Yk/Yv.
// ---------------------------------------------------------------------------
template <int MODE>
__global__ __launch_bounds__(256) void mfma_gemm(
    const bf16* __restrict__ A, const bf16* __restrict__ BT,
    const float* __restrict__ b0, const float* __restrict__ b1,
    const float* __restrict__ b2,
    float* __restrict__ Yf,
    bf16* __restrict__ Yq, bf16* __restrict__ Yk, bf16* __restrict__ Yv,
    int M, int N, int K) {
    __shared__ bf16 As[128 * 32];
    __shared__ bf16 Bs[128 * 32];

    const int t = threadIdx.x;
    const int lane = t & 63;
    const int w = t >> 6;
    const int wm = w >> 1, wn = w & 1;
    const int m0 = blockIdx.y * 128, n0 = blockIdx.x * 128;

    const int srow = lane >> 2;
    const int scol = (lane & 3) * 8;

    f32x4 acc[4][4];
#pragma unroll
    for (int i = 0; i < 4; i++)
#pragma unroll
        for (int j = 0; j < 4; j++) acc[i][j] = (f32x4)0.f;

    const int lr = lane & 15;
    const int lq = lane >> 4;

    for (int k0 = 0; k0 < K; k0 += 32) {
#pragma unroll
        for (int s = 0; s < 2; s++) {
            const int c = w * 2 + s;
            gld_lds16(A + (size_t)(m0 + c * 16 + srow) * K + k0 + scol, As + c * 512);
            gld_lds16(BT + (size_t)(n0 + c * 16 + srow) * K + k0 + scol, Bs + c * 512);
        }
        __syncthreads();
        short8 af[4], bfv[4];
#pragma unroll
        for (int i = 0; i < 4; i++)
            af[i] = *(const short8*)(As + (wm * 64 + i * 16 + lr) * 32 + lq * 8);
#pragma unroll
        for (int j = 0; j < 4; j++)
            bfv[j] = *(const short8*)(Bs + (wn * 64 + j * 16 + lr) * 32 + lq * 8);
#pragma unroll
        for (int i = 0; i < 4; i++)
#pragma unroll
            for (int j = 0; j < 4; j++)
                acc[i][j] = __builtin_amdgcn_mfma_f32_16x16x32_bf16(af[i], bfv[j],
                                                                    acc[i][j], 0, 0, 0);
        __syncthreads();
    }

    if (MODE == 0) {
#pragma unroll
        for (int j = 0; j < 4; j++) {
            const int col = n0 + wn * 64 + j * 16 + lr;
            const float bj = b0[col];
#pragma unroll
            for (int i = 0; i < 4; i++) {
                const int row = m0 + wm * 64 + i * 16 + lq * 4;
#pragma unroll
                for (int r = 0; r < 4; r++)
                    Yf[(size_t)(row + r) * N + col] = acc[i][j][r] + bj;
            }
        }
    } else {
        bf16* outp; const float* bias; int ldc, c0;
        if (n0 < 2048)      { outp = Yq; bias = b0; ldc = 2048; c0 = n0; }
        else if (n0 < 2560) { outp = Yk; bias = b1; ldc = 512;  c0 = n0 - 2048; }
        else                { outp = Yv; bias = b2; ldc = 512;  c0 = n0 - 2560; }
#pragma unroll
        for (int j = 0; j < 4; j++) {
            const int col = c0 + wn * 64 + j * 16 + lr;
            const float bj = bias[col];
#pragma unroll
            for (int i = 0; i < 4; i++) {
                const int row = m0 + wm * 64 + i * 16 + lq * 4;
#pragma unroll
                for (int r = 0; r < 4; r++)
                    outp[(size_t)(row + r) * ldc + col] = toB(acc[i][j][r] + bj);
            }
        }
    }
}

// ---------------------------------------------------------------------------
// RoPE in-place on bf16 buffer laid out (B*S rows, H heads, HD).
// ---------------------------------------------------------------------------
__global__ void rope_kernel(bf16* __restrict__ buf, int H) {
    int idx = blockIdx.x * blockDim.x + threadIdx.x;
    int total = BB * SS * H * (HD / 2);
    if (idx >= total) return;
    int d2 = idx & 63;
    int hh = idx >> 6;
    int h = hh % H;
    int row = hh / H;
    int s = row % SS;
    float freq = expf(-logf(10000.f) * (float)(2 * d2) / (float)HD);
    float ang = (float)s * freq;
    float c = cosf(ang), sn = sinf(ang);
    size_t base = ((size_t)row * H + h) * HD + 2 * d2;
    float xe = toF(buf[base]);
    float xo = toF(buf[base + 1]);
    buf[base]     = toB(xe * c - xo * sn);
    buf[base + 1] = toB(xe * sn + xo * c);
}

// ---------------------------------------------------------------------------
// MFMA flash attention, windowed causal, GQA. Block = 4 waves = 64 queries;
// wave w owns 16 queries (q0+16w..+15) with private online softmax. K-chunk
// = 64 keys. QK^T: A=Q (register frags), B=K (LDS, gld_lds16-staged).
// P round-trips through wave-private LDS (C-layout -> A-layout, m120).
// V staged transposed Vt[d][key] (stride 72) so PV B-frags are b128 reads.
// IN-PLACE: Oout aliases Q; each block only rewrites its own 64 q-rows of
// head h, and only reads them (into registers) at block start.
// ---------------------------------------------------------------------------
__global__ __launch_bounds__(256) void attn_mfma(const bf16* __restrict__ Q,
                                                 const bf16* __restrict__ K,
                                                 const bf16* __restrict__ V,
                                                 bf16* __restrict__ Oout) {
    __shared__ bf16 Ks[64 * 128];      // [key][d]          16384 B
    __shared__ bf16 Vt[128 * 72];      // [d][key] pad 72   18432 B
    __shared__ bf16 Ps[4 * 16 * 72];   // per-wave P tile    9216 B

    const int t = threadIdx.x;
    const int lane = t & 63;
    const int w = t >> 6;
    const int q0 = blockIdx.x * 64;
    const int h = blockIdx.y;
    const int b = blockIdx.z;
    const int hkv = h >> 2;
    const int lr = lane & 15;          // fragment row/col
    const int lq = lane >> 4;          // quad
    const float scale = 0.08838834764831845f;  // 1/sqrt(128)

    // Q fragments: A[m=lr][k=lq*8+j (+32*kstep)], 16B-aligned global loads
    short8 aq[4];
    {
        const int q = q0 + w * 16 + lr;
        const bf16* qp = Q + (((size_t)b * SS + q) * NQ + h) * HD + lq * 8;
#pragma unroll
        for (int ks = 0; ks < 4; ks++) aq[ks] = *(const short8*)(qp + ks * 32);
    }

    f32x4 Oa[8];
#pragma unroll
    for (int nb = 0; nb < 8; nb++) Oa[nb] = (f32x4)0.f;
    float mprev[4] = {-3.0e38f, -3.0e38f, -3.0e38f, -3.0e38f};
    float lsum[4] = {0.f, 0.f, 0.f, 0.f};

    bf16* Pw = Ps + w * 16 * 72;
    const int jstart = (q0 >= WINDOW) ? (q0 - WINDOW) : 0;

    for (int c0 = jstart; c0 <= q0; c0 += 64) {
        __syncthreads();   // protect Ks/Vt from previous iteration's readers
        // stage K chunk: wave w stages rows [w*16, w*16+16)
#pragma unroll
        for (int s = 0; s < 4; s++) {
            const bf16* gk = K +
                (((size_t)b * SS + c0 + w * 16 + s * 4 + (lane >> 4)) * NKV + hkv) * HD +
                (lane & 15) * 8;
            gld_lds16(gk, Ks + (w * 16 + s * 4) * 128);
        }
        // stage V transposed: thread t covers key=t&63, d-groups (t>>6)*8 + it*32
        {
            const int key = t & 63;
            const int dg = (t >> 6) * 8;
            const bf16* gv = V + (((size_t)b * SS + c0 + key) * NKV + hkv) * HD + dg;
#pragma unroll
            for (int it = 0; it < 4; it++) {
                short8 vv = *(const short8*)(gv + it * 32);
#pragma unroll
                for (int j = 0; j < 8; j++)
                    Vt[(dg + it * 32 + j) * 72 + key] = ((const bf16*)&vv)[j];
            }
        }
        __syncthreads();

        // scores: 16q x 64k, C-layout (col=key=lr, row=q=lq*4+r)
        f32x4 sa[4];
#pragma unroll
        for (int nb = 0; nb < 4; nb++) sa[nb] = (f32x4)0.f;
#pragma unroll
        for (int ks = 0; ks < 4; ks++) {
#pragma unroll
            for (int nb = 0; nb < 4; nb++) {
                short8 bk = *(const short8*)(Ks + (nb * 16 + lr) * 128 + ks * 32 + lq * 8);
                sa[nb] = __builtin_amdgcn_mfma_f32_16x16x32_bf16(aq[ks], bk, sa[nb], 0, 0, 0);
            }
        }

        // mask + online softmax (rows lq*4+r; reduce across lane bits 0-3)
        const int rowb = q0 + w * 16 + lq * 4;
        float pr[4][4], alpha[4];
#pragma unroll
        for (int r = 0; r < 4; r++) {
            const int row = rowb + r;
            float sv[4];
            float mx = -3.0e38f;
#pragma unroll
            for (int nb = 0; nb < 4; nb++) {
                const int col = c0 + nb * 16 + lr;
                const bool valid = (col <= row) && (row - col <= WINDOW);
                const float s = valid ? sa[nb][r] * scale : -3.0e38f;
                sv[nb] = s;
                mx = fmaxf(mx, s);
            }
#pragma unroll
            for (int off = 1; off < 16; off <<= 1) mx = fmaxf(mx, __shfl_xor(mx, off, 64));
            const float mn = fmaxf(fmaxf(mprev[r], mx), -1.0e30f);
            alpha[r] = __expf(mprev[r] - mn);
            mprev[r] = mn;
            float rs = 0.f;
#pragma unroll
            for (int nb = 0; nb < 4; nb++) {
                const float p = __expf(sv[nb] - mn);
                pr[r][nb] = p;
                rs += p;
            }
#pragma unroll
            for (int off = 1; off < 16; off <<= 1) rs += __shfl_xor(rs, off, 64);
            lsum[r] = lsum[r] * alpha[r] + rs;
        }

        // P: C-layout -> LDS [q][key] (wave-private; same-wave RAW, compiler
        // orders + waits via aliasing)
#pragma unroll
        for (int r = 0; r < 4; r++)
#pragma unroll
            for (int nb = 0; nb < 4; nb++)
                Pw[(lq * 4 + r) * 72 + nb * 16 + lr] = toB(pr[r][nb]);

        // rescale O, then PV: A=P (b128 from Pw), B=V (b128 from Vt)
#pragma unroll
        for (int nb = 0; nb < 8; nb++)
#pragma unroll
            for (int r = 0; r < 4; r++) Oa[nb][r] *= alpha[r];
#pragma unroll
        for (int ks = 0; ks < 2; ks++) {
            short8 pa = *(const short8*)(Pw + lr * 72 + ks * 32 + lq * 8);
#pragma unroll
            for (int nb = 0; nb < 8; nb++) {
                short8 bv = *(const short8*)(Vt + (nb * 16 + lr) * 72 + ks * 32 + lq * 8);
                Oa[nb] = __builtin_amdgcn_mfma_f32_16x16x32_bf16(pa, bv, Oa[nb], 0, 0, 0);
            }
        }
    }

    // epilogue: normalize + store (in-place over this block's own Q rows)
    float linv[4];
#pragma unroll
    for (int r = 0; r < 4; r++) linv[r] = 1.f / lsum[r];
    const int rowb = q0 + w * 16 + lq * 4;
#pragma unroll
    for (int nb = 0; nb < 8; nb++)
#pragma unroll
        for (int r = 0; r < 4; r++)
            Oout[(((size_t)b * SS + rowb + r) * NQ + h) * HD + nb * 16 + lr] =
                toB(Oa[nb][r] * linv[r]);
}

// ---------------------------------------------------------------------------
extern "C" void kernel_launch(void* const* d_in, const int* in_sizes, int n_in,
                              void* d_out, int out_size, void* d_ws, size_t ws_size,
                              hipStream_t stream) {
    const float* x  = (const float*)d_in[0];
    const float* Wq = (const float*)d_in[1];
    const float* bq = (const float*)d_in[2];
    const float* Wk = (const float*)d_in[3];
    const float* bk = (const float*)d_in[4];
    const float* Wv = (const float*)d_in[5];
    const float* bv = (const float*)d_in[6];
    const float* Wo = (const float*)d_in[7];
    const float* bo = (const float*)d_in[8];
    float* out = (float*)d_out;

    const int M   = BB * SS;       // 4096
    const int DQ  = NQ * HD;       // 2048
    const int DKV = NKV * HD;      // 512
    const int NPK = DQ + 2 * DKV;  // 3072

    bf16* xb     = (bf16*)d_ws;                       // 4096*2048
    bf16* WqkvT  = xb + (size_t)M * EE;               // 3072*2048
    bf16* WoT    = WqkvT + (size_t)NPK * EE;          // 2048*2048
    bf16* Qb     = WoT + (size_t)EE * DQ;             // 4096*2048 (attn out in-place)
    bf16* Kb     = Qb + (size_t)M * DQ;               // 4096*512
    bf16* Vb     = Kb + (size_t)M * DKV;              // 4096*512

    convert_bf16<<<(M * EE / 4 + 255) / 256, 256, 0, stream>>>(x, xb, M * EE);
    convert_transpose<<<dim3(DQ / 32, EE / 32), 256, 0, stream>>>(Wq, WqkvT, EE, DQ);
    convert_transpose<<<dim3(DKV / 32, EE / 32), 256, 0, stream>>>(
        Wk, WqkvT + (size_t)DQ * EE, EE, DKV);
    convert_transpose<<<dim3(DKV / 32, EE / 32), 256, 0, stream>>>(
        Wv, WqkvT + (size_t)(DQ + DKV) * EE, EE, DKV);
    convert_transpose<<<dim3(DQ / 32, DQ / 32), 256, 0, stream>>>(Wo, WoT, DQ, EE);

    mfma_gemm<1><<<dim3(NPK / 128, M / 128), 256, 0, stream>>>(
        xb, WqkvT, bq, bk, bv, nullptr, Qb, Kb, Vb, M, NPK, EE);

    rope_kernel<<<(BB * SS * NQ * (HD / 2) + 255) / 256, 256, 0, stream>>>(Qb, NQ);
    rope_kernel<<<(BB * SS * NKV * (HD / 2) + 255) / 256, 256, 0, stream>>>(Kb, NKV);

    attn_mfma<<<dim3(SS / 64, NQ, BB), 256, 0, stream>>>(Qb, Kb, Vb, Qb);

    mfma_gemm<0><<<dim3(EE / 128, M / 128), 256, 0, stream>>>(
        Qb, WoT, bo, nullptr, nullptr, out, nullptr, nullptr, nullptr, M, EE, DQ);
}

// Round 6
// 329.352 us; speedup vs baseline: 6.7975x; 1.1485x over previous
//
#include <hip/hip_runtime.h>
#include <hip/hip_bf16.h>
#include <math.h>

#define BB 2
#define SS 2048
#define EE 2048
#define NQ 16
#define NKV 4
#define HD 128
#define WINDOW 512

typedef __hip_bfloat16 bf16;
typedef short short8 __attribute__((ext_vector_type(8)));   // 8 bf16 (4 VGPRs)
typedef float f32x4 __attribute__((ext_vector_type(4)));

__device__ __forceinline__ float toF(bf16 v) { return __bfloat162float(v); }
__device__ __forceinline__ bf16 toB(float v) { return __float2bfloat16(v); }

// async global->LDS, 16B per lane. LDS dest = wave-uniform base + lane*16.
__device__ __forceinline__ void gld_lds16(const void* g, void* l) {
    __builtin_amdgcn_global_load_lds(
        (const __attribute__((address_space(1))) void*)g,
        (__attribute__((address_space(3))) void*)l, 16, 0, 0);
}

// ---------------------------------------------------------------------------
// fp32 -> bf16 elementwise (n % 4 == 0)
// ---------------------------------------------------------------------------
__global__ __launch_bounds__(256) void convert_bf16(const float* __restrict__ in,
                                                    bf16* __restrict__ out, int n) {
    int i = (blockIdx.x * 256 + threadIdx.x) * 4;
    if (i >= n) return;
    const float4 v = *(const float4*)(in + i);
    bf16 o[4] = {toB(v.x), toB(v.y), toB(v.z), toB(v.w)};
    *(uint2*)(out + i) = *(const uint2*)o;
}

// ---------------------------------------------------------------------------
// fp32 [K][N] -> bf16 [N][K] transpose. Generic (Wo).
// ---------------------------------------------------------------------------
__global__ __launch_bounds__(256) void convert_transpose(const float* __restrict__ in,
                                                         bf16* __restrict__ out,
                                                         int K, int N) {
    __shared__ float tile[32][33];
    const int t = threadIdx.x;
    const int tx = t & 31, ty = t >> 5;   // 32 x 8
    const int n0 = blockIdx.x * 32, k0 = blockIdx.y * 32;
#pragma unroll
    for (int r = 0; r < 4; r++)
        tile[ty + r * 8][tx] = in[(size_t)(k0 + ty + r * 8) * N + n0 + tx];
    __syncthreads();
#pragma unroll
    for (int r = 0; r < 4; r++)
        out[(size_t)(n0 + ty + r * 8) * K + k0 + tx] = toB(tile[tx][ty + r * 8]);
}

// ---------------------------------------------------------------------------
// Fused Wq/Wk/Wv transpose into packed [3072][2048] bf16. Region boundaries
// (2048, 2560) are 32-aligned so a tile never straddles sources.
// ---------------------------------------------------------------------------
__global__ __launch_bounds__(256) void convert_transpose_qkv(
    const float* __restrict__ Wq, const float* __restrict__ Wk,
    const float* __restrict__ Wv, bf16* __restrict__ out) {
    __shared__ float tile[32][33];
    const int t = threadIdx.x;
    const int tx = t & 31, ty = t >> 5;
    const int n0 = blockIdx.x * 32, k0 = blockIdx.y * 32;
    const float* src; int N, nl0;
    if (n0 < 2048)      { src = Wq; N = 2048; nl0 = n0; }
    else if (n0 < 2560) { src = Wk; N = 512;  nl0 = n0 - 2048; }
    else                { src = Wv; N = 512;  nl0 = n0 - 2560; }
#pragma unroll
    for (int r = 0; r < 4; r++)
        tile[ty + r * 8][tx] = src[(size_t)(k0 + ty + r * 8) * N + nl0 + tx];
    __syncthreads();
#pragma unroll
    for (int r = 0; r < 4; r++)
        out[(size_t)(n0 + ty + r * 8) * 2048 + k0 + tx] = toB(tile[tx][ty + r * 8]);
}

// ---------------------------------------------------------------------------
// MFMA bf16 GEMM (m97 structure): 128x128 tile, BK=32, 4 waves 2x2, each wave
// 4x4 grid of 16x16x32 MFMAs. A [M,K] bf16, BT [N,K] bf16 (B transposed).
// LDS XOR swizzle: k-group g of row r lives at slot g ^ ((r>>1)&3) -> frag
// reads hit 8 bank-quads 2-way (free) instead of 2 banks 8-way.
// MODE 0: fp32 out + bias. MODE 1: packed QKV split -> bf16 Yq/Yk/Yv with
// RoPE fused into the Q/K epilogue (pair exchange via shfl_xor lane^1).
// ---------------------------------------------------------------------------
template <int MODE>
__global__ __launch_bounds__(256) void mfma_gemm(
    const bf16* __restrict__ A, const bf16* __restrict__ BT,
    const float* __restrict__ b0, const float* __restrict__ b1,
    const float* __restrict__ b2,
    float* __restrict__ Yf,
    bf16* __restrict__ Yq, bf16* __restrict__ Yk, bf16* __restrict__ Yv,
    int M, int N, int K) {
    __shared__ bf16 As[128 * 32];
    __shared__ bf16 Bs[128 * 32];

    const int t = threadIdx.x;
    const int lane = t & 63;
    const int w = t >> 6;
    const int wm = w >> 1, wn = w & 1;
    const int m0 = blockIdx.y * 128, n0 = blockIdx.x * 128;

    const int srow = lane >> 2;                       // row within 16-row chunk
    const int sg   = lane & 3;                        // LDS slot (fixed by lane)
    const int scol = (sg ^ ((srow >> 1) & 3)) * 8;    // swizzled source k-group

    f32x4 acc[4][4];
#pragma unroll
    for (int i = 0; i < 4; i++)
#pragma unroll
        for (int j = 0; j < 4; j++) acc[i][j] = (f32x4)0.f;

    const int lr = lane & 15;
    const int lq = lane >> 4;
    const int slotr = (lq ^ ((lr >> 1) & 3)) * 8;     // reader's swizzled slot

    for (int k0 = 0; k0 < K; k0 += 32) {
#pragma unroll
        for (int s = 0; s < 2; s++) {
            const int c = w * 2 + s;
            gld_lds16(A + (size_t)(m0 + c * 16 + srow) * K + k0 + scol, As + c * 512);
            gld_lds16(BT + (size_t)(n0 + c * 16 + srow) * K + k0 + scol, Bs + c * 512);
        }
        __syncthreads();
        short8 af[4], bfv[4];
#pragma unroll
        for (int i = 0; i < 4; i++)
            af[i] = *(const short8*)(As + (wm * 64 + i * 16 + lr) * 32 + slotr);
#pragma unroll
        for (int j = 0; j < 4; j++)
            bfv[j] = *(const short8*)(Bs + (wn * 64 + j * 16 + lr) * 32 + slotr);
#pragma unroll
        for (int i = 0; i < 4; i++)
#pragma unroll
            for (int j = 0; j < 4; j++)
                acc[i][j] = __builtin_amdgcn_mfma_f32_16x16x32_bf16(af[i], bfv[j],
                                                                    acc[i][j], 0, 0, 0);
        __syncthreads();
    }

    if (MODE == 0) {
#pragma unroll
        for (int j = 0; j < 4; j++) {
            const int col = n0 + wn * 64 + j * 16 + lr;
            const float bj = b0[col];
#pragma unroll
            for (int i = 0; i < 4; i++) {
                const int row = m0 + wm * 64 + i * 16 + lq * 4;
#pragma unroll
                for (int r = 0; r < 4; r++)
                    Yf[(size_t)(row + r) * N + col] = acc[i][j][r] + bj;
            }
        }
    } else {
        bf16* outp; const float* bias; int ldc, c0; bool dorope;
        if (n0 < 2048)      { outp = Yq; bias = b0; ldc = 2048; c0 = n0;        dorope = true; }
        else if (n0 < 2560) { outp = Yk; bias = b1; ldc = 512;  c0 = n0 - 2048; dorope = true; }
        else                { outp = Yv; bias = b2; ldc = 512;  c0 = n0 - 2560; dorope = false; }
#pragma unroll
        for (int j = 0; j < 4; j++) {
            const int col = c0 + wn * 64 + j * 16 + lr;
            const float bj = bias[col];
            if (dorope) {
                // RoPE: pair (2m, 2m+1); even lane holds x_e, odd lane x_o.
                const int d2 = (col & 127) >> 1;
                const bool odd = col & 1;
                const float freq = __expf(-0.14384103622589045f * (float)d2); // ln(1e4)*2/128
#pragma unroll
                for (int i = 0; i < 4; i++) {
                    const int row = m0 + wm * 64 + i * 16 + lq * 4;
#pragma unroll
                    for (int r = 0; r < 4; r++) {
                        const float v = acc[i][j][r] + bj;
                        const float p = __shfl_xor(v, 1, 64);
                        const float ang = (float)((row + r) & (SS - 1)) * freq;
                        float sn, cs;
                        __sincosf(ang, &sn, &cs);
                        const float o = odd ? (p * sn + v * cs) : (v * cs - p * sn);
                        outp[(size_t)(row + r) * ldc + col] = toB(o);
                    }
                }
            } else {
#pragma unroll
                for (int i = 0; i < 4; i++) {
                    const int row = m0 + wm * 64 + i * 16 + lq * 4;
#pragma unroll
                    for (int r = 0; r < 4; r++)
                        outp[(size_t)(row + r) * ldc + col] = toB(acc[i][j][r] + bj);
                }
            }
        }
    }
}

// ---------------------------------------------------------------------------
// MFMA flash attention, windowed causal, GQA (unchanged from round 5).
// Block = 4 waves = 64 queries; wave-private online softmax; 64-key chunks.
// IN-PLACE: Oout aliases Q (block reads its own 64 rows up front).
// ---------------------------------------------------------------------------
__global__ __launch_bounds__(256) void attn_mfma(const bf16* __restrict__ Q,
                                                 const bf16* __restrict__ K,
                                                 const bf16* __restrict__ V,
                                                 bf16* __restrict__ Oout) {
    __shared__ bf16 Ks[64 * 128];      // [key][d]
    __shared__ bf16 Vt[128 * 72];      // [d][key] pad 72
    __shared__ bf16 Ps[4 * 16 * 72];   // per-wave P tile

    const int t = threadIdx.x;
    const int lane = t & 63;
    const int w = t >> 6;
    const int q0 = blockIdx.x * 64;
    const int h = blockIdx.y;
    const int b = blockIdx.z;
    const int hkv = h >> 2;
    const int lr = lane & 15;
    const int lq = lane >> 4;
    const float scale = 0.08838834764831845f;  // 1/sqrt(128)

    short8 aq[4];
    {
        const int q = q0 + w * 16 + lr;
        const bf16* qp = Q + (((size_t)b * SS + q) * NQ + h) * HD + lq * 8;
#pragma unroll
        for (int ks = 0; ks < 4; ks++) aq[ks] = *(const short8*)(qp + ks * 32);
    }

    f32x4 Oa[8];
#pragma unroll
    for (int nb = 0; nb < 8; nb++) Oa[nb] = (f32x4)0.f;
    float mprev[4] = {-3.0e38f, -3.0e38f, -3.0e38f, -3.0e38f};
    float lsum[4] = {0.f, 0.f, 0.f, 0.f};

    bf16* Pw = Ps + w * 16 * 72;
    const int jstart = (q0 >= WINDOW) ? (q0 - WINDOW) : 0;

    for (int c0 = jstart; c0 <= q0; c0 += 64) {
        __syncthreads();
#pragma unroll
        for (int s = 0; s < 4; s++) {
            const bf16* gk = K +
                (((size_t)b * SS + c0 + w * 16 + s * 4 + (lane >> 4)) * NKV + hkv) * HD +
                (lane & 15) * 8;
            gld_lds16(gk, Ks + (w * 16 + s * 4) * 128);
        }
        {
            const int key = t & 63;
            const int dg = (t >> 6) * 8;
            const bf16* gv = V + (((size_t)b * SS + c0 + key) * NKV + hkv) * HD + dg;
#pragma unroll
            for (int it = 0; it < 4; it++) {
                short8 vv = *(const short8*)(gv + it * 32);
#pragma unroll
                for (int j = 0; j < 8; j++)
                    Vt[(dg + it * 32 + j) * 72 + key] = ((const bf16*)&vv)[j];
            }
        }
        __syncthreads();

        f32x4 sa[4];
#pragma unroll
        for (int nb = 0; nb < 4; nb++) sa[nb] = (f32x4)0.f;
#pragma unroll
        for (int ks = 0; ks < 4; ks++) {
#pragma unroll
            for (int nb = 0; nb < 4; nb++) {
                short8 bk = *(const short8*)(Ks + (nb * 16 + lr) * 128 + ks * 32 + lq * 8);
                sa[nb] = __builtin_amdgcn_mfma_f32_16x16x32_bf16(aq[ks], bk, sa[nb], 0, 0, 0);
            }
        }

        const int rowb = q0 + w * 16 + lq * 4;
        float pr[4][4], alpha[4];
#pragma unroll
        for (int r = 0; r < 4; r++) {
            const int row = rowb + r;
            float sv[4];
            float mx = -3.0e38f;
#pragma unroll
            for (int nb = 0; nb < 4; nb++) {
                const int col = c0 + nb * 16 + lr;
                const bool valid = (col <= row) && (row - col <= WINDOW);
                const float s = valid ? sa[nb][r] * scale : -3.0e38f;
                sv[nb] = s;
                mx = fmaxf(mx, s);
            }
#pragma unroll
            for (int off = 1; off < 16; off <<= 1) mx = fmaxf(mx, __shfl_xor(mx, off, 64));
            const float mn = fmaxf(fmaxf(mprev[r], mx), -1.0e30f);
            alpha[r] = __expf(mprev[r] - mn);
            mprev[r] = mn;
            float rs = 0.f;
#pragma unroll
            for (int nb = 0; nb < 4; nb++) {
                const float p = __expf(sv[nb] - mn);
                pr[r][nb] = p;
                rs += p;
            }
#pragma unroll
            for (int off = 1; off < 16; off <<= 1) rs += __shfl_xor(rs, off, 64);
            lsum[r] = lsum[r] * alpha[r] + rs;
        }

#pragma unroll
        for (int r = 0; r < 4; r++)
#pragma unroll
            for (int nb = 0; nb < 4; nb++)
                Pw[(lq * 4 + r) * 72 + nb * 16 + lr] = toB(pr[r][nb]);

#pragma unroll
        for (int nb = 0; nb < 8; nb++)
#pragma unroll
            for (int r = 0; r < 4; r++) Oa[nb][r] *= alpha[r];
#pragma unroll
        for (int ks = 0; ks < 2; ks++) {
            short8 pa = *(const short8*)(Pw + lr * 72 + ks * 32 + lq * 8);
#pragma unroll
            for (int nb = 0; nb < 8; nb++) {
                short8 bv = *(const short8*)(Vt + (nb * 16 + lr) * 72 + ks * 32 + lq * 8);
                Oa[nb] = __builtin_amdgcn_mfma_f32_16x16x32_bf16(pa, bv, Oa[nb], 0, 0, 0);
            }
        }
    }

    float linv[4];
#pragma unroll
    for (int r = 0; r < 4; r++) linv[r] = 1.f / lsum[r];
    const int rowb = q0 + w * 16 + lq * 4;
#pragma unroll
    for (int nb = 0; nb < 8; nb++)
#pragma unroll
        for (int r = 0; r < 4; r++)
            Oout[(((size_t)b * SS + rowb + r) * NQ + h) * HD + nb * 16 + lr] =
                toB(Oa[nb][r] * linv[r]);
}

// ---------------------------------------------------------------------------
extern "C" void kernel_launch(void* const* d_in, const int* in_sizes, int n_in,
                              void* d_out, int out_size, void* d_ws, size_t ws_size,
                              hipStream_t stream) {
    const float* x  = (const float*)d_in[0];
    const float* Wq = (const float*)d_in[1];
    const float* bq = (const float*)d_in[2];
    const float* Wk = (const float*)d_in[3];
    const float* bk = (const float*)d_in[4];
    const float* Wv = (const float*)d_in[5];
    const float* bv = (const float*)d_in[6];
    const float* Wo = (const float*)d_in[7];
    const float* bo = (const float*)d_in[8];
    float* out = (float*)d_out;

    const int M   = BB * SS;       // 4096
    const int DQ  = NQ * HD;       // 2048
    const int DKV = NKV * HD;      // 512
    const int NPK = DQ + 2 * DKV;  // 3072

    bf16* xb     = (bf16*)d_ws;                       // 4096*2048
    bf16* WqkvT  = xb + (size_t)M * EE;               // 3072*2048
    bf16* WoT    = WqkvT + (size_t)NPK * EE;          // 2048*2048
    bf16* Qb     = WoT + (size_t)EE * DQ;             // 4096*2048 (attn out in-place)
    bf16* Kb     = Qb + (size_t)M * DQ;               // 4096*512
    bf16* Vb     = Kb + (size_t)M * DKV;              // 4096*512

    convert_bf16<<<(M * EE / 4 + 255) / 256, 256, 0, stream>>>(x, xb, M * EE);
    convert_transpose_qkv<<<dim3(NPK / 32, EE / 32), 256, 0, stream>>>(Wq, Wk, Wv, WqkvT);
    convert_transpose<<<dim3(DQ / 32, DQ / 32), 256, 0, stream>>>(Wo, WoT, DQ, EE);

    // fused QKV projection + bias + RoPE (MFMA)
    mfma_gemm<1><<<dim3(NPK / 128, M / 128), 256, 0, stream>>>(
        xb, WqkvT, bq, bk, bv, nullptr, Qb, Kb, Vb, M, NPK, EE);

    attn_mfma<<<dim3(SS / 64, NQ, BB), 256, 0, stream>>>(Qb, Kb, Vb, Qb);

    mfma_gemm<0><<<dim3(EE / 128, M / 128), 256, 0, stream>>>(
        Qb, WoT, bo, nullptr, nullptr, out, nullptr, nullptr, nullptr, M, EE, DQ);
}